// Round 1
// baseline (52.456 us; speedup 1.0000x reference)
//
#include <hip/hip_runtime.h>

#define BB 16
#define LL 4096
#define DD 768
#define CB 320
#define CHUNKS 128
#define ROWS (LL / CHUNKS)   // 32

// ---------------- Kernel 1: histogram + weights + sum (one block per batch) ----
__global__ __launch_bounds__(256) void k_weights(const int2* __restrict__ vq,
                                                 float* __restrict__ w,
                                                 float* __restrict__ sinv) {
    __shared__ int cnt[2 * CB];
    __shared__ float wsum[4];
    const int b = blockIdx.x;
    const int t = threadIdx.x;

    for (int i = t; i < 2 * CB; i += 256) cnt[i] = 0;
    __syncthreads();

    const int2* vb = vq + (size_t)b * LL;
    for (int l = t; l < LL; l += 256) {
        int2 v = vb[l];
        atomicAdd(&cnt[v.x], 1);
        atomicAdd(&cnt[CB + v.y], 1);
    }
    __syncthreads();

    float lsum = 0.f;
    for (int l = t; l < LL; l += 256) {
        int2 v = vb[l];
        float wi = 1.0f / (float)(cnt[v.x] + cnt[CB + v.y]);
        w[(size_t)b * LL + l] = wi;
        lsum += wi;
    }
    // wave (64-lane) reduce, then cross-wave via LDS
    for (int o = 32; o > 0; o >>= 1) lsum += __shfl_down(lsum, o, 64);
    if ((t & 63) == 0) wsum[t >> 6] = lsum;
    __syncthreads();
    if (t == 0) {
        float s = wsum[0] + wsum[1] + wsum[2] + wsum[3];
        sinv[b] = 1.0f / s;
    }
}

// ---------------- Kernel 2: partial weighted sums over L-chunks ----------------
// grid = BB*CHUNKS blocks, 192 threads; thread t owns float4 at d = 4*t.
__global__ __launch_bounds__(192) void k_partial(const float* __restrict__ x,
                                                 const float* __restrict__ w,
                                                 float* __restrict__ part) {
    const int blk = blockIdx.x;
    const int b = blk / CHUNKS;
    const int c = blk % CHUNKS;
    const int t = threadIdx.x;

    // x slice: input_feature[b, 1, :, :]
    const float4* xb = (const float4*)(x + ((size_t)(b * 2 + 1) * LL) * DD);
    const float* wb = w + (size_t)b * LL;

    float ax = 0.f, ay = 0.f, az = 0.f, aw = 0.f;
    const int l0 = c * ROWS;
#pragma unroll 4
    for (int r = 0; r < ROWS; ++r) {
        const int l = l0 + r;
        const float wi = wb[l];
        float4 v = xb[(size_t)l * (DD / 4) + t];
        ax = fmaf(wi, v.x, ax);
        ay = fmaf(wi, v.y, ay);
        az = fmaf(wi, v.z, az);
        aw = fmaf(wi, v.w, aw);
    }
    float4* pp = (float4*)(part + (size_t)blk * DD);
    float4 o; o.x = ax; o.y = ay; o.z = az; o.w = aw;
    pp[t] = o;
}

// ---------------- Kernel 3: reduce partials, scale by 1/S[b] -------------------
// BB*DD/4 = 3072 float4 lanes -> 12 blocks x 256 threads
__global__ __launch_bounds__(256) void k_reduce(const float* __restrict__ part,
                                                const float* __restrict__ sinv,
                                                float* __restrict__ out) {
    const int i = blockIdx.x * 256 + threadIdx.x;   // 0 .. BB*DD/4-1
    const int b = i / (DD / 4);
    const int d4 = i % (DD / 4);
    const float4* p = (const float4*)part;

    float ax = 0.f, ay = 0.f, az = 0.f, aw = 0.f;
#pragma unroll 8
    for (int c = 0; c < CHUNKS; ++c) {
        float4 v = p[((size_t)(b * CHUNKS + c)) * (DD / 4) + d4];
        ax += v.x; ay += v.y; az += v.z; aw += v.w;
    }
    const float s = sinv[b];
    float4 o; o.x = ax * s; o.y = ay * s; o.z = az * s; o.w = aw * s;
    ((float4*)out)[i] = o;
}

extern "C" void kernel_launch(void* const* d_in, const int* in_sizes, int n_in,
                              void* d_out, int out_size, void* d_ws, size_t ws_size,
                              hipStream_t stream) {
    const float* x = (const float*)d_in[0];       // (16, 2, 4096, 768) fp32
    // d_in[1] = input_lengths: unused by the reference
    const int2* vq = (const int2*)d_in[2];        // (16, 4096, 2) int32

    // workspace layout (floats)
    float* w = (float*)d_ws;                      // BB*LL floats
    float* sinv = w + (size_t)BB * LL;            // BB floats (pad to 16)
    float* part = sinv + 16;                      // BB*CHUNKS*DD floats, 16B-aligned

    float* out = (float*)d_out;                   // (16, 768) fp32

    k_weights<<<BB, 256, 0, stream>>>(vq, w, sinv);
    k_partial<<<BB * CHUNKS, 192, 0, stream>>>(x, w, part);
    k_reduce<<<(BB * DD / 4) / 256, 256, 0, stream>>>(part, sinv, out);
}

// Round 2
// 42.558 us; speedup vs baseline: 1.2326x; 1.2326x over previous
//
#include <hip/hip_runtime.h>

#define BB 16
#define LL 4096
#define DD 768
#define CB 320
#define CHUNKS 128
#define ROWS (LL / CHUNKS)   // 32

// ---------------- Kernel 1: histogram + weights + sum (one block per batch) ----
// 1024 threads: each thread owns 4 (idx_x, idx_y) pairs held in registers
// across the histogram and weight passes (no vq re-read).
__global__ __launch_bounds__(1024) void k_weights(const int2* __restrict__ vq,
                                                  float* __restrict__ w,
                                                  float* __restrict__ sinv) {
    __shared__ int cnt[2 * CB];
    __shared__ float wsum[16];
    const int b = blockIdx.x;
    const int t = threadIdx.x;

    if (t < 2 * CB) cnt[t] = 0;
    __syncthreads();

    const int2* vb = vq + (size_t)b * LL;
    int2 v[4];
#pragma unroll
    for (int k = 0; k < 4; ++k) v[k] = vb[t + k * 1024];
#pragma unroll
    for (int k = 0; k < 4; ++k) {
        atomicAdd(&cnt[v[k].x], 1);
        atomicAdd(&cnt[CB + v[k].y], 1);
    }
    __syncthreads();

    float lsum = 0.f;
#pragma unroll
    for (int k = 0; k < 4; ++k) {
        float wi = 1.0f / (float)(cnt[v[k].x] + cnt[CB + v[k].y]);
        w[(size_t)b * LL + t + k * 1024] = wi;
        lsum += wi;
    }
    for (int o = 32; o > 0; o >>= 1) lsum += __shfl_down(lsum, o, 64);
    if ((t & 63) == 0) wsum[t >> 6] = lsum;
    __syncthreads();
    if (t == 0) {
        float s = 0.f;
#pragma unroll
        for (int i = 0; i < 16; ++i) s += wsum[i];
        sinv[b] = 1.0f / s;
    }
}

// ---------------- Kernel 2: partial weighted sums over L-chunks ----------------
// grid = BB*CHUNKS blocks, 192 threads; thread t owns float4 at d = 4*t.
__global__ __launch_bounds__(192) void k_partial(const float* __restrict__ x,
                                                 const float* __restrict__ w,
                                                 float* __restrict__ part) {
    const int blk = blockIdx.x;
    const int b = blk / CHUNKS;
    const int c = blk % CHUNKS;
    const int t = threadIdx.x;

    // x slice: input_feature[b, 1, :, :]
    const float4* xb = (const float4*)(x + ((size_t)(b * 2 + 1) * LL) * DD);
    const float* wb = w + (size_t)b * LL;

    float ax = 0.f, ay = 0.f, az = 0.f, aw = 0.f;
    const int l0 = c * ROWS;
#pragma unroll 8
    for (int r = 0; r < ROWS; ++r) {
        const int l = l0 + r;
        const float wi = wb[l];
        float4 v = xb[(size_t)l * (DD / 4) + t];
        ax = fmaf(wi, v.x, ax);
        ay = fmaf(wi, v.y, ay);
        az = fmaf(wi, v.z, az);
        aw = fmaf(wi, v.w, aw);
    }
    float4* pp = (float4*)(part + (size_t)blk * DD);
    float4 o; o.x = ax; o.y = ay; o.z = az; o.w = aw;
    pp[t] = o;
}

// ---------------- Kernel 3: reduce partials, scale by 1/S[b] -------------------
// 48 blocks x 256 threads. Block covers 64 consecutive (b,d4) lanes;
// 4 chunk-groups of 32 chunks each, combined through LDS.
// (DD/4 = 192 is a multiple of 64, so each block sees a single batch b.)
__global__ __launch_bounds__(256) void k_reduce(const float* __restrict__ part,
                                                const float* __restrict__ sinv,
                                                float* __restrict__ out) {
    __shared__ float4 red[3][64];
    const int t = threadIdx.x;
    const int lane = t & 63;
    const int cg = t >> 6;                        // 0..3
    const int i = blockIdx.x * 64 + lane;         // 0 .. BB*DD/4-1
    const int b = i / (DD / 4);
    const int d4 = i % (DD / 4);
    const float4* p = (const float4*)part;

    float ax = 0.f, ay = 0.f, az = 0.f, aw = 0.f;
    const int c0 = cg * (CHUNKS / 4);
#pragma unroll 8
    for (int c = c0; c < c0 + CHUNKS / 4; ++c) {
        float4 v = p[((size_t)(b * CHUNKS + c)) * (DD / 4) + d4];
        ax += v.x; ay += v.y; az += v.z; aw += v.w;
    }
    if (cg > 0) {
        float4 o; o.x = ax; o.y = ay; o.z = az; o.w = aw;
        red[cg - 1][lane] = o;
    }
    __syncthreads();
    if (cg == 0) {
        float4 r0 = red[0][lane], r1 = red[1][lane], r2 = red[2][lane];
        ax += r0.x + r1.x + r2.x;
        ay += r0.y + r1.y + r2.y;
        az += r0.z + r1.z + r2.z;
        aw += r0.w + r1.w + r2.w;
        const float s = sinv[b];
        float4 o; o.x = ax * s; o.y = ay * s; o.z = az * s; o.w = aw * s;
        ((float4*)out)[i] = o;
    }
}

extern "C" void kernel_launch(void* const* d_in, const int* in_sizes, int n_in,
                              void* d_out, int out_size, void* d_ws, size_t ws_size,
                              hipStream_t stream) {
    const float* x = (const float*)d_in[0];       // (16, 2, 4096, 768) fp32
    // d_in[1] = input_lengths: unused by the reference
    const int2* vq = (const int2*)d_in[2];        // (16, 4096, 2) int32

    // workspace layout (floats)
    float* w = (float*)d_ws;                      // BB*LL floats
    float* sinv = w + (size_t)BB * LL;            // BB floats (pad to 16)
    float* part = sinv + 16;                      // BB*CHUNKS*DD floats, 16B-aligned

    float* out = (float*)d_out;                   // (16, 768) fp32

    k_weights<<<BB, 1024, 0, stream>>>(vq, w, sinv);
    k_partial<<<BB * CHUNKS, 192, 0, stream>>>(x, w, part);
    k_reduce<<<48, 256, 0, stream>>>(part, sinv, out);
}